// Round 5
// baseline (255.691 us; speedup 1.0000x reference)
//
#include <hip/hip_runtime.h>
#include <stdint.h>

// Problem constants (fixed by setup_inputs)
#define BATCH 64
#define NPTS  131072
#define MPTS  2048
#define WORDS_PB (NPTS / 64)       // 2048 mask words per batch
#define P1_PPB 2048                // points per pass1 block
#define P1_BLOCKS (BATCH * NPTS / P1_PPB)   // 4096

// ---------------- Threefry-2x32-20, exactly as jax/_src/prng.py ----------------
struct U2 { uint32_t a, b; };

__host__ __device__ constexpr U2 tf2x32(uint32_t k0, uint32_t k1, uint32_t x0, uint32_t x1) {
  uint32_t ks0 = k0, ks1 = k1, ks2 = k0 ^ k1 ^ 0x1BD11BDAu;
  x0 += ks0; x1 += ks1;
  const int rotA[4] = {13, 15, 26, 6};
  const int rotB[4] = {17, 29, 16, 24};
  for (int r = 0; r < 4; ++r) { x0 += x1; x1 = (x1 << rotA[r]) | (x1 >> (32 - rotA[r])); x1 ^= x0; }
  x0 += ks1; x1 += ks2 + 1u;
  for (int r = 0; r < 4; ++r) { x0 += x1; x1 = (x1 << rotB[r]) | (x1 >> (32 - rotB[r])); x1 ^= x0; }
  x0 += ks2; x1 += ks0 + 2u;
  for (int r = 0; r < 4; ++r) { x0 += x1; x1 = (x1 << rotA[r]) | (x1 >> (32 - rotA[r])); x1 ^= x0; }
  x0 += ks0; x1 += ks1 + 3u;
  for (int r = 0; r < 4; ++r) { x0 += x1; x1 = (x1 << rotB[r]) | (x1 >> (32 - rotB[r])); x1 ^= x0; }
  x0 += ks1; x1 += ks2 + 4u;
  for (int r = 0; r < 4; ++r) { x0 += x1; x1 = (x1 << rotA[r]) | (x1 >> (32 - rotA[r])); x1 ^= x0; }
  x0 += ks2; x1 += ks0 + 5u;
  return U2{x0, x1};
}

// Async global->LDS DMA, 16B per lane. LDS dest must be wave-uniform;
// lane i's 16B lands at ldsbase + i*16. Zero VGPRs consumed by results,
// concurrency tracked in vmcnt (queue depth 63) — decouples outstanding
// loads from register pressure (the R1-R4 limiter).
__device__ __forceinline__ void load_lds16(const void* g, void* l) {
  __builtin_amdgcn_global_load_lds(
      (const __attribute__((address_space(1))) void*)g,
      (__attribute__((address_space(3))) void*)l, 16, 0, 0);
}

// ---------------- Pass 1: streaming mask + masked xyz sums ----------------
// Stage 2048 points (pc 32KB + logits 16KB = 48KB LDS) via global_load_lds,
// one barrier, then consume from LDS. 3 blocks/CU co-resident -> ~96KB/CU
// of DMA in flight while another block drains its barrier.
__global__ __launch_bounds__(256) void pass1_kernel(
    const float4* __restrict__ pc, const float* __restrict__ lg,
    float* __restrict__ sums, unsigned long long* __restrict__ maskWords) {
  int blk = blockIdx.x;
  int t = threadIdx.x;
  int wv = t >> 6, lane = t & 63;
  size_t blockBase = (size_t)blk * P1_PPB;   // global point index base
  int b = (int)(blockBase >> 17);            // / NPTS
  size_t off = blockBase & (NPTS - 1);       // in-batch point offset
  const float4* pcg = pc + blockBase;
  const float*  l0g = lg + (size_t)b * (2 * NPTS) + off;
  const float*  l1g = l0g + NPTS;

  __shared__ float4 sPC[P1_PPB];   // 32 KB
  __shared__ float  sL0[P1_PPB];   // 8 KB
  __shared__ float  sL1[P1_PPB];   // 8 KB

  // Stage: each wave issues 12 async 1KB DMA insts (8 pc + 2 l0 + 2 l1).
#pragma unroll
  for (int k = 0; k < 8; ++k) {
    int p = wv * 512 + k * 64;               // wave-uniform point offset
    load_lds16(pcg + p + lane, &sPC[p]);
  }
#pragma unroll
  for (int k = 0; k < 2; ++k) {
    int f = wv * 512 + k * 256;              // wave-uniform float offset
    load_lds16((const float4*)(l0g + f) + lane, &sL0[f]);
    load_lds16((const float4*)(l1g + f) + lane, &sL1[f]);
  }
  __syncthreads();                           // vmcnt(0) drain + barrier

  // Consume from LDS: 8 points per thread, lane-contiguous (ballot order ok).
  float sx = 0.f, sy = 0.f, sz = 0.f;
#pragma unroll
  for (int k = 0; k < 8; ++k) {
    int idx = k * 256 + t;
    float a0 = sL0[idx];
    float a1 = sL1[idx];
    float4 q = sPC[idx];
    bool m = a0 < a1;
    unsigned long long bal = __ballot(m);
    if (lane == 0) maskWords[(blockBase + idx) >> 6] = bal;
    if (m) { sx += q.x; sy += q.y; sz += q.z; }
  }

  // wave (64-lane) reduce, then cross-wave via LDS
  for (int o = 32; o; o >>= 1) {
    sx += __shfl_down(sx, o, 64);
    sy += __shfl_down(sy, o, 64);
    sz += __shfl_down(sz, o, 64);
  }
  __shared__ float ssx[4], ssy[4], ssz[4];
  if (lane == 0) { ssx[wv] = sx; ssy[wv] = sy; ssz[wv] = sz; }
  __syncthreads();
  if (t == 0) {
    atomicAdd(&sums[b * 3 + 0], ssx[0] + ssx[1] + ssx[2] + ssx[3]);
    atomicAdd(&sums[b * 3 + 1], ssy[0] + ssy[1] + ssy[2] + ssy[3]);
    atomicAdd(&sums[b * 3 + 2], ssz[0] + ssz[1] + ssz[2] + ssz[3]);
  }
}

// ---------------- Pass 2: word-level exclusive prefix + count + mean ----------------
__global__ __launch_bounds__(256) void pass2_kernel(
    const unsigned long long* __restrict__ maskWords, const float* __restrict__ sums,
    uint32_t* __restrict__ wordOff, int* __restrict__ cnt,
    float* __restrict__ mean, float* __restrict__ out) {
  int b = blockIdx.x, t = threadIdx.x;
  int lane = t & 63, wv = t >> 6;
  const unsigned long long* mw = maskWords + (size_t)b * WORDS_PB;
  int base = t * 8;
  int p[8];
  int local = 0;
#pragma unroll
  for (int k = 0; k < 8; ++k) { p[k] = __popcll(mw[base + k]); local += p[k]; }

  // wave-level inclusive scan of `local`
  int x = local;
#pragma unroll
  for (int o = 1; o < 64; o <<= 1) {
    int y = __shfl_up(x, o, 64);
    if (lane >= o) x += y;
  }
  __shared__ int wsum[4];
  if (lane == 63) wsum[wv] = x;
  __syncthreads();
  int add = 0;
#pragma unroll
  for (int u = 0; u < 4; ++u) add += (u < wv) ? wsum[u] : 0;
  int run = add + x - local;               // exclusive prefix for this thread's 8 words
  uint32_t* wo = wordOff + (size_t)b * WORDS_PB;
#pragma unroll
  for (int k = 0; k < 8; ++k) { wo[base + k] = (uint32_t)run; run += p[k]; }

  if (t == 0) {
    int ct = wsum[0] + wsum[1] + wsum[2] + wsum[3];
    cnt[b] = ct;
    float d  = fmaxf((float)ct, 1.0f);
    float mx = sums[b * 3 + 0] / d;
    float my = sums[b * 3 + 1] / d;
    float mz = sums[b * 3 + 2] / d;
    mean[b * 3 + 0] = mx; mean[b * 3 + 1] = my; mean[b * 3 + 2] = mz;
    float* om = out + (size_t)BATCH * MPTS * 3 + (size_t)b * 3;
    om[0] = mx; om[1] = my; om[2] = mz;
  }
}

// ---------------- Pass 3: threefry randint + rank-select + gather ----------------
__global__ __launch_bounds__(256) void pass3_kernel(
    const float4* __restrict__ pc, const int* __restrict__ cnt,
    const float* __restrict__ mean, const uint32_t* __restrict__ wordOff,
    const unsigned long long* __restrict__ maskWords,
    float* __restrict__ out) {
  int blk = blockIdx.x;
  int b = blk >> 3;                        // 8 blocks per batch (2048/256)
  int t = threadIdx.x;
  int j = (blk & 7) * 256 + t;
  int gid = b * MPTS + j;

  __shared__ uint32_t sOff[WORDS_PB];      // 8 KiB: full word-level prefix for batch b
  __shared__ float sMean[3];
  __shared__ int sCnt;
  const uint32_t* wo = wordOff + (size_t)b * WORDS_PB;
#pragma unroll
  for (int k = 0; k < 8; ++k) sOff[t + k * 256] = wo[t + k * 256];
  if (t < 3)  sMean[t] = mean[b * 3 + t];
  if (t == 0) sCnt = cnt[b];
  __syncthreads();

  int cb = sCnt;
  float ox, oy, oz;
  if (cb == 0) {
    ox = oy = oz = (float)b;               // reference fills empty batches with batch id
  } else {
    // jax.random.randint(key(42),(B,M),0,max(cnt,1)) — partitionable threefry
    constexpr U2 K1 = tf2x32(0u, 42u, 0u, 0u);   // split(key)[0]
    constexpr U2 K2 = tf2x32(0u, 42u, 0u, 1u);   // split(key)[1]
    uint32_t span = (uint32_t)cb;
    U2 h = tf2x32(K1.a, K1.b, 0u, (uint32_t)gid);
    U2 l = tf2x32(K2.a, K2.b, 0u, (uint32_t)gid);
    uint32_t hb = h.a ^ h.b;               // higher_bits (32-bit fold)
    uint32_t lb = l.a ^ l.b;               // lower_bits
    uint32_t mul = 65536u % span;
    mul = (mul * mul) % span;              // uint32 wrap, exactly as lax
    uint32_t off = ((hb % span) * mul + (lb % span)) % span;
    int r = (j < cb && cb <= MPTS) ? j : (int)off;

    // binary search: largest w with sOff[w] <= r (sOff[0]==0)
    int lo = 0;
#pragma unroll
    for (int step = 1024; step; step >>= 1) {
      int nxt = lo + step;
      if (nxt < WORDS_PB && sOff[nxt] <= (uint32_t)r) lo = nxt;
    }
    int rem = r - (int)sOff[lo];
    unsigned long long w = maskWords[(size_t)b * WORDS_PB + lo];

    // branchless 64-bit rank-select of the rem-th set bit
    uint32_t cur = (uint32_t)w;
    int bitbase = 0;
    int c = __popc(cur);
    if (rem >= c) { rem -= c; cur = (uint32_t)(w >> 32); bitbase = 32; }
    c = __popc(cur & 0xFFFFu); if (rem >= c) { rem -= c; cur >>= 16; bitbase += 16; }
    c = __popc(cur & 0xFFu);   if (rem >= c) { rem -= c; cur >>= 8;  bitbase += 8;  }
    c = __popc(cur & 0xFu);    if (rem >= c) { rem -= c; cur >>= 4;  bitbase += 4;  }
    c = __popc(cur & 0x3u);    if (rem >= c) { rem -= c; cur >>= 2;  bitbase += 2;  }
    c = (int)(cur & 1u);       if (rem >= c) {           cur >>= 1;  bitbase += 1;  }
    int idx = lo * 64 + bitbase;

    float4 p = pc[(size_t)b * NPTS + idx];
    ox = p.x - sMean[0]; oy = p.y - sMean[1]; oz = p.z - sMean[2];
  }
  float* o = out + (size_t)gid * 3;
  o[0] = ox; o[1] = oy; o[2] = oz;
}

// ---------------- launch ----------------
extern "C" void kernel_launch(void* const* d_in, const int* in_sizes, int n_in,
                              void* d_out, int out_size, void* d_ws, size_t ws_size,
                              hipStream_t stream) {
  const float4* pc = (const float4*)d_in[0];   // (B, N, 4) float32
  const float*  lg = (const float*)d_in[1];    // (B, 2, N) float32
  float* out = (float*)d_out;                  // obj (B,M,3) then mean (B,3)

  char* w = (char*)d_ws;
  float*    sums    = (float*)(w + 0);                     // 64*3 floats (768 B)
  int*      cnt     = (int*)(w + 1024);                    // 64 ints
  float*    mean    = (float*)(w + 2048);                  // 64*3 floats
  uint32_t* wordOff = (uint32_t*)(w + 4096);               // 64*2048 u32 = 512 KiB
  unsigned long long* maskWords =
      (unsigned long long*)(w + 4096 + 524288);            // 64*2048 u64 = 1 MiB

  hipMemsetAsync(sums, 0, 768, stream);  // ws is poisoned 0xAA; sums accumulates

  pass1_kernel<<<P1_BLOCKS, 256, 0, stream>>>(pc, lg, sums, maskWords);
  pass2_kernel<<<BATCH, 256, 0, stream>>>(maskWords, sums, wordOff, cnt, mean, out);
  pass3_kernel<<<(BATCH * MPTS) / 256, 256, 0, stream>>>(pc, cnt, mean, wordOff, maskWords, out);
}

// Round 6
// 246.775 us; speedup vs baseline: 1.0361x; 1.0361x over previous
//
#include <hip/hip_runtime.h>
#include <stdint.h>

// Problem constants (fixed by setup_inputs)
#define BATCH 64
#define NPTS  131072
#define MPTS  2048
#define WORDS_PB (NPTS / 64)       // 2048 mask words per batch
#define P1_BLOCKS 1024             // 4 per CU; 16 blocks per batch
#define P1_SPAN   8192             // contiguous points per block (8192*16 = NPTS)
#define P1_ITERS  (P1_SPAN / 256)  // 32

// ---------------- Threefry-2x32-20, exactly as jax/_src/prng.py ----------------
struct U2 { uint32_t a, b; };

__host__ __device__ constexpr U2 tf2x32(uint32_t k0, uint32_t k1, uint32_t x0, uint32_t x1) {
  uint32_t ks0 = k0, ks1 = k1, ks2 = k0 ^ k1 ^ 0x1BD11BDAu;
  x0 += ks0; x1 += ks1;
  const int rotA[4] = {13, 15, 26, 6};
  const int rotB[4] = {17, 29, 16, 24};
  for (int r = 0; r < 4; ++r) { x0 += x1; x1 = (x1 << rotA[r]) | (x1 >> (32 - rotA[r])); x1 ^= x0; }
  x0 += ks1; x1 += ks2 + 1u;
  for (int r = 0; r < 4; ++r) { x0 += x1; x1 = (x1 << rotB[r]) | (x1 >> (32 - rotB[r])); x1 ^= x0; }
  x0 += ks2; x1 += ks0 + 2u;
  for (int r = 0; r < 4; ++r) { x0 += x1; x1 = (x1 << rotA[r]) | (x1 >> (32 - rotA[r])); x1 ^= x0; }
  x0 += ks0; x1 += ks1 + 3u;
  for (int r = 0; r < 4; ++r) { x0 += x1; x1 = (x1 << rotB[r]) | (x1 >> (32 - rotB[r])); x1 ^= x0; }
  x0 += ks1; x1 += ks2 + 4u;
  for (int r = 0; r < 4; ++r) { x0 += x1; x1 = (x1 << rotA[r]) | (x1 >> (32 - rotA[r])); x1 ^= x0; }
  x0 += ks2; x1 += ks0 + 5u;
  return U2{x0, x1};
}

// ---------------- Pass 1: persistent streaming mask + masked xyz sums ----------------
// 1024 blocks (4/CU), each owns 8192 CONTIGUOUS points within one batch and
// loops 32 iterations — long-lived waves in memory-pipeline steady state
// (the m13 6.3 TB/s copy structure), instead of 4096 one-shot blocks whose
// startup/teardown dominated (R1-R5 all plateaued at ~2.3 TB/s).
__global__ __launch_bounds__(256) void pass1_kernel(
    const float4* __restrict__ pc, const float* __restrict__ lg,
    float* __restrict__ sums, unsigned long long* __restrict__ maskWords) {
  int g = blockIdx.x;
  int t = threadIdx.x;
  int lane = t & 63, wv = t >> 6;
  int b = g >> 4;                            // 16 blocks per batch
  size_t base = (size_t)g * P1_SPAN;         // global point index base
  size_t inb  = base & (NPTS - 1);           // in-batch offset
  const float*  l0g = lg + (size_t)b * (2 * NPTS) + inb;
  const float*  l1g = l0g + NPTS;
  const float4* pcg = pc + base;

  float sx = 0.f, sy = 0.f, sz = 0.f;
#pragma unroll 4
  for (int k = 0; k < P1_ITERS; ++k) {
    int idx = k * 256 + t;
    float a0 = l0g[idx];
    float a1 = l1g[idx];
    float4 q = pcg[idx];
    bool m = a0 < a1;
    unsigned long long bal = __ballot(m);
    if (lane == 0) maskWords[(base + idx) >> 6] = bal;
    if (m) { sx += q.x; sy += q.y; sz += q.z; }
  }

  // wave (64-lane) reduce, then cross-wave via LDS
  for (int o = 32; o; o >>= 1) {
    sx += __shfl_down(sx, o, 64);
    sy += __shfl_down(sy, o, 64);
    sz += __shfl_down(sz, o, 64);
  }
  __shared__ float ssx[4], ssy[4], ssz[4];
  if (lane == 0) { ssx[wv] = sx; ssy[wv] = sy; ssz[wv] = sz; }
  __syncthreads();
  if (t == 0) {
    atomicAdd(&sums[b * 3 + 0], ssx[0] + ssx[1] + ssx[2] + ssx[3]);
    atomicAdd(&sums[b * 3 + 1], ssy[0] + ssy[1] + ssy[2] + ssy[3]);
    atomicAdd(&sums[b * 3 + 2], ssz[0] + ssz[1] + ssz[2] + ssz[3]);
  }
}

// ---------------- Pass 2: word-level exclusive prefix + count + mean ----------------
__global__ __launch_bounds__(256) void pass2_kernel(
    const unsigned long long* __restrict__ maskWords, const float* __restrict__ sums,
    uint32_t* __restrict__ wordOff, int* __restrict__ cnt,
    float* __restrict__ mean, float* __restrict__ out) {
  int b = blockIdx.x, t = threadIdx.x;
  int lane = t & 63, wv = t >> 6;
  const unsigned long long* mw = maskWords + (size_t)b * WORDS_PB;
  int base = t * 8;
  int p[8];
  int local = 0;
#pragma unroll
  for (int k = 0; k < 8; ++k) { p[k] = __popcll(mw[base + k]); local += p[k]; }

  // wave-level inclusive scan of `local`
  int x = local;
#pragma unroll
  for (int o = 1; o < 64; o <<= 1) {
    int y = __shfl_up(x, o, 64);
    if (lane >= o) x += y;
  }
  __shared__ int wsum[4];
  if (lane == 63) wsum[wv] = x;
  __syncthreads();
  int add = 0;
#pragma unroll
  for (int u = 0; u < 4; ++u) add += (u < wv) ? wsum[u] : 0;
  int run = add + x - local;               // exclusive prefix for this thread's 8 words
  uint32_t* wo = wordOff + (size_t)b * WORDS_PB;
#pragma unroll
  for (int k = 0; k < 8; ++k) { wo[base + k] = (uint32_t)run; run += p[k]; }

  if (t == 0) {
    int ct = wsum[0] + wsum[1] + wsum[2] + wsum[3];
    cnt[b] = ct;
    float d  = fmaxf((float)ct, 1.0f);
    float mx = sums[b * 3 + 0] / d;
    float my = sums[b * 3 + 1] / d;
    float mz = sums[b * 3 + 2] / d;
    mean[b * 3 + 0] = mx; mean[b * 3 + 1] = my; mean[b * 3 + 2] = mz;
    float* om = out + (size_t)BATCH * MPTS * 3 + (size_t)b * 3;
    om[0] = mx; om[1] = my; om[2] = mz;
  }
}

// ---------------- Pass 3: threefry randint + rank-select + gather ----------------
__global__ __launch_bounds__(256) void pass3_kernel(
    const float4* __restrict__ pc, const int* __restrict__ cnt,
    const float* __restrict__ mean, const uint32_t* __restrict__ wordOff,
    const unsigned long long* __restrict__ maskWords,
    float* __restrict__ out) {
  int blk = blockIdx.x;
  int b = blk >> 3;                        // 8 blocks per batch (2048/256)
  int t = threadIdx.x;
  int j = (blk & 7) * 256 + t;
  int gid = b * MPTS + j;

  __shared__ uint32_t sOff[WORDS_PB];      // 8 KiB: full word-level prefix for batch b
  __shared__ float sMean[3];
  __shared__ int sCnt;
  const uint32_t* wo = wordOff + (size_t)b * WORDS_PB;
#pragma unroll
  for (int k = 0; k < 8; ++k) sOff[t + k * 256] = wo[t + k * 256];
  if (t < 3)  sMean[t] = mean[b * 3 + t];
  if (t == 0) sCnt = cnt[b];
  __syncthreads();

  int cb = sCnt;
  float ox, oy, oz;
  if (cb == 0) {
    ox = oy = oz = (float)b;               // reference fills empty batches with batch id
  } else {
    // jax.random.randint(key(42),(B,M),0,max(cnt,1)) — partitionable threefry
    constexpr U2 K1 = tf2x32(0u, 42u, 0u, 0u);   // split(key)[0]
    constexpr U2 K2 = tf2x32(0u, 42u, 0u, 1u);   // split(key)[1]
    uint32_t span = (uint32_t)cb;
    U2 h = tf2x32(K1.a, K1.b, 0u, (uint32_t)gid);
    U2 l = tf2x32(K2.a, K2.b, 0u, (uint32_t)gid);
    uint32_t hb = h.a ^ h.b;               // higher_bits (32-bit fold)
    uint32_t lb = l.a ^ l.b;               // lower_bits
    uint32_t mul = 65536u % span;
    mul = (mul * mul) % span;              // uint32 wrap, exactly as lax
    uint32_t off = ((hb % span) * mul + (lb % span)) % span;
    int r = (j < cb && cb <= MPTS) ? j : (int)off;

    // binary search: largest w with sOff[w] <= r (sOff[0]==0)
    int lo = 0;
#pragma unroll
    for (int step = 1024; step; step >>= 1) {
      int nxt = lo + step;
      if (nxt < WORDS_PB && sOff[nxt] <= (uint32_t)r) lo = nxt;
    }
    int rem = r - (int)sOff[lo];
    unsigned long long w = maskWords[(size_t)b * WORDS_PB + lo];

    // branchless 64-bit rank-select of the rem-th set bit
    uint32_t cur = (uint32_t)w;
    int bitbase = 0;
    int c = __popc(cur);
    if (rem >= c) { rem -= c; cur = (uint32_t)(w >> 32); bitbase = 32; }
    c = __popc(cur & 0xFFFFu); if (rem >= c) { rem -= c; cur >>= 16; bitbase += 16; }
    c = __popc(cur & 0xFFu);   if (rem >= c) { rem -= c; cur >>= 8;  bitbase += 8;  }
    c = __popc(cur & 0xFu);    if (rem >= c) { rem -= c; cur >>= 4;  bitbase += 4;  }
    c = __popc(cur & 0x3u);    if (rem >= c) { rem -= c; cur >>= 2;  bitbase += 2;  }
    c = (int)(cur & 1u);       if (rem >= c) {           cur >>= 1;  bitbase += 1;  }
    int idx = lo * 64 + bitbase;

    float4 p = pc[(size_t)b * NPTS + idx];
    ox = p.x - sMean[0]; oy = p.y - sMean[1]; oz = p.z - sMean[2];
  }
  float* o = out + (size_t)gid * 3;
  o[0] = ox; o[1] = oy; o[2] = oz;
}

// ---------------- launch ----------------
extern "C" void kernel_launch(void* const* d_in, const int* in_sizes, int n_in,
                              void* d_out, int out_size, void* d_ws, size_t ws_size,
                              hipStream_t stream) {
  const float4* pc = (const float4*)d_in[0];   // (B, N, 4) float32
  const float*  lg = (const float*)d_in[1];    // (B, 2, N) float32
  float* out = (float*)d_out;                  // obj (B,M,3) then mean (B,3)

  char* w = (char*)d_ws;
  float*    sums    = (float*)(w + 0);                     // 64*3 floats (768 B)
  int*      cnt     = (int*)(w + 1024);                    // 64 ints
  float*    mean    = (float*)(w + 2048);                  // 64*3 floats
  uint32_t* wordOff = (uint32_t*)(w + 4096);               // 64*2048 u32 = 512 KiB
  unsigned long long* maskWords =
      (unsigned long long*)(w + 4096 + 524288);            // 64*2048 u64 = 1 MiB

  hipMemsetAsync(sums, 0, 768, stream);  // ws is poisoned 0xAA; sums accumulates

  pass1_kernel<<<P1_BLOCKS, 256, 0, stream>>>(pc, lg, sums, maskWords);
  pass2_kernel<<<BATCH, 256, 0, stream>>>(maskWords, sums, wordOff, cnt, mean, out);
  pass3_kernel<<<(BATCH * MPTS) / 256, 256, 0, stream>>>(pc, cnt, mean, wordOff, maskWords, out);
}